// Round 1
// baseline (288.327 us; speedup 1.0000x reference)
//
#include <hip/hip_runtime.h>
#include <math.h>

#define Bn 4096
#define Tn 512
#define Vn 57
#define En 20
#define Hn 128
#define On 18
#define ROWS 16          // batch rows per block (= MFMA N)
#define NTHR 256         // 4 waves, ONE per SIMD: no issue contention, cheap barrier
#define NBLK (Bn / ROWS) // 256 blocks -> 1 per CU (LDS pad keeps it that way)
#define KC 5             // K = 160 = 128 (h) + 20 (emb) + 1 (bias) + 11 pad
#define ESTR 40          // embT row stride (halfs)
#define XSTR 513         // staged x row stride (ints): bank=(r+t)%32, conflict-free
#define HFSTR 132        // final-h fp32 row stride
#define ASCALE 2.8853900817779268f   // 2*log2(e): folds tanh's 2x and log2e mul into A

typedef _Float16 half8  __attribute__((ext_vector_type(8)));
typedef __fp16   fp16x2 __attribute__((ext_vector_type(2)));   // cvt_pkrtz native type
typedef float    floatx4 __attribute__((ext_vector_type(4)));

// acc is pre-scaled by 2*log2e: tanh(x) = 1 - 2/(1+2^(2x*log2e))
__device__ __forceinline__ float tanh_scaled(float z) {
    float e = __builtin_amdgcn_exp2f(z);          // v_exp_f32
    float r = __builtin_amdgcn_rcpf(e + 1.0f);    // v_rcp_f32
    return fmaf(-2.0f, r, 1.0f);
}

__device__ __forceinline__ unsigned pk_u32(fp16x2 v) {
    union { fp16x2 h; unsigned u; } c; c.h = v; return c.u;
}

// (256, 1): 4 waves = 1/SIMD. VGPR cap 512; demand ~120 -> no spill.
__launch_bounds__(NTHR, 1)
__global__ void rnn_mfma_kernel(const int* __restrict__ x,
                                const int* __restrict__ xlen,
                                const float* __restrict__ emb,
                                const float* __restrict__ W_ih,
                                const float* __restrict__ W_hh,
                                const float* __restrict__ b_ih,
                                const float* __restrict__ b_hh,
                                const float* __restrict__ W_out,
                                const float* __restrict__ b_out,
                                float* __restrict__ out)
{
    // Exchange buffers: frag kc for lane l lives at exB[buf][kc][l] (uint4 = half8).
    // Writes/reads are 64 consecutive 16B lanes -> conflict-free. Double-buffered:
    // one barrier per step.
    __shared__ __align__(16) uint4    exB[2][4][64];
    __shared__ __align__(16) _Float16 sEmb[Vn * ESTR];  // cols 0..19 emb, 20 = 1.0, rest 0
    __shared__ __align__(16) float    sHf[ROWS * HFSTR];
    __shared__ int   sX[ROWS * XSTR];
    __shared__ float sLogit[ROWS][On];
    __shared__ float sMLS[ROWS];
    __shared__ float sPad[6800];   // 27.2KB pad: total ~82.4KB -> exactly 1 block/CU

    const int tid  = threadIdx.x;
    const int blk  = blockIdx.x;
    const int row0 = blk * ROWS;

    // volatile touch keeps sPad (and the 1-block/CU LDS footprint) alive
    ((volatile float*)sPad)[tid % 6800] = 0.0f;

    const int w    = tid >> 6;       // wave 0..3 -> owns h features [32w, 32w+32)
    const int lane = tid & 63;
    const int n    = lane & 15;      // batch row (B/C col) AND A fragment row m
    const int q    = lane >> 4;      // quad

    // ---- A operand (static, 40 VGPRs): PERMUTED row mapping so that the C output
    // of tile (w,b), lane (q,n), reg i == h feature 32w+8q+4b+i. Then the packed
    // tanh output of lane (q,n) is EXACTLY B-fragment kc=w (k = 32w+8q+j) -- the
    // recurrent state never needs a cross-lane shuffle or scatter, only one
    // ds_write_b128 per wave per step to share with the other 3 waves.
    //   A frag layout: row m = lane&15, k = 32*kc + 8*(lane>>4) + i.
    //   Row m of tile (w,b) loads weight row f = 32w + 8*(m>>2) + 4b + (m&3).
    // K ordering stays the standard feature order (k<128: W_hh col k; 128..147:
    // W_ih; 148: fused bias via constant-1 in the xe fragment). Pre-scaled by
    // 2*log2e (tanh input fusion).
    half8 Ah[2][KC];
    const int fA0 = 32 * w + 8 * (n >> 2) + (n & 3);
    #pragma unroll
    for (int b = 0; b < 2; ++b) {
        const int f = fA0 + 4 * b;
        #pragma unroll
        for (int kc = 0; kc < 4; ++kc) {
            const float* p = &W_hh[f * Hn + kc * 32 + q * 8];
            #pragma unroll
            for (int i = 0; i < 8; ++i)
                Ah[b][kc][i] = (_Float16)(p[i] * ASCALE);
        }
        #pragma unroll
        for (int i = 0; i < 8; ++i) {
            int e = q * 8 + i;
            float v = 0.0f;
            if (e < En)       v = W_ih[f * En + e];
            else if (e == 20) v = b_ih[f] + b_hh[f];
            Ah[b][4][i] = (_Float16)(v * ASCALE);
        }
    }

    // ---- build embT (fp16) with constant-1 bias column
    for (int idx = tid; idx < Vn * 32; idx += NTHR) {
        int c = idx >> 5, j = idx & 31;
        float v = (j < En) ? emb[c * En + j] : (j == 20 ? 1.0f : 0.0f);
        sEmb[c * ESTR + j] = (_Float16)v;
    }
    // ---- stage vocab ids (int4-vectorized; 512 % 4 == 0 -> no row crossing)
    for (int idx = tid * 4; idx < ROWS * Tn; idx += NTHR * 4) {
        int4 v = *(const int4*)&x[row0 * Tn + idx];
        int r = idx >> 9, t = idx & 511;
        sX[r * XSTR + t]     = v.x;
        sX[r * XSTR + t + 1] = v.y;
        sX[r * XSTR + t + 2] = v.z;
        sX[r * XSTR + t + 3] = v.w;
    }
    // ---- zero both exchange buffers (h0 = 0)
    for (int idx = tid; idx < 2 * 4 * 64; idx += NTHR)
        ((uint4*)exB)[idx] = make_uint4(0u, 0u, 0u, 0u);
    __syncthreads();

    const int Lmax  = xlen[row0];    // sorted descending -> block trip count
    const int len_n = xlen[row0 + n];

    // ---- xe pipeline straight into registers (no staging waves):
    // lane (q,n) needs xe cols 8q..8q+7 of token x[n][t] -> one half8 gather.
    int   idN;
    half8 xeC;
    {
        int id0 = sX[n * XSTR];
        xeC = *(const half8*)&sEmb[id0 * ESTR + 8 * q];
        idN = sX[n * XSTR + (Lmax > 1 ? 1 : 0)];
    }

    float hreg[8] = {0.f, 0.f, 0.f, 0.f, 0.f, 0.f, 0.f, 0.f};

    // one step: read all 4 h-frags from exB[BR], 10 MFMA (2 tiles x 5 kc, E/O
    // split per tile -> dep depth 3), tanh+freeze+pack, publish own frag to
    // exB[BW], ONE barrier. Buffers are compile-time (t unrolled by 2).
    #define RNN_STEP(BR, BW, t)                                                   \
    {                                                                             \
        half8 bf0 = *(const half8*)&exB[BR][0][lane];                             \
        half8 bf1 = *(const half8*)&exB[BR][1][lane];                             \
        half8 bf2 = *(const half8*)&exB[BR][2][lane];                             \
        half8 bf3 = *(const half8*)&exB[BR][3][lane];                             \
        half8 xeN = *(const half8*)&sEmb[idN * ESTR + 8 * q];                     \
        int idN2 = sX[n * XSTR + min((t) + 2, Lmax - 1)];                         \
        floatx4 aE0 = {0.f,0.f,0.f,0.f}, aO0 = {0.f,0.f,0.f,0.f};                 \
        floatx4 aE1 = {0.f,0.f,0.f,0.f}, aO1 = {0.f,0.f,0.f,0.f};                 \
        aE0 = __builtin_amdgcn_mfma_f32_16x16x32_f16(Ah[0][0], bf0, aE0, 0,0,0);  \
        aE1 = __builtin_amdgcn_mfma_f32_16x16x32_f16(Ah[1][0], bf0, aE1, 0,0,0);  \
        aO0 = __builtin_amdgcn_mfma_f32_16x16x32_f16(Ah[0][1], bf1, aO0, 0,0,0);  \
        aO1 = __builtin_amdgcn_mfma_f32_16x16x32_f16(Ah[1][1], bf1, aO1, 0,0,0);  \
        aE0 = __builtin_amdgcn_mfma_f32_16x16x32_f16(Ah[0][2], bf2, aE0, 0,0,0);  \
        aE1 = __builtin_amdgcn_mfma_f32_16x16x32_f16(Ah[1][2], bf2, aE1, 0,0,0);  \
        aO0 = __builtin_amdgcn_mfma_f32_16x16x32_f16(Ah[0][3], bf3, aO0, 0,0,0);  \
        aO1 = __builtin_amdgcn_mfma_f32_16x16x32_f16(Ah[1][3], bf3, aO1, 0,0,0);  \
        aE0 = __builtin_amdgcn_mfma_f32_16x16x32_f16(Ah[0][4], xeC, aE0, 0,0,0);  \
        aE1 = __builtin_amdgcn_mfma_f32_16x16x32_f16(Ah[1][4], xeC, aE1, 0,0,0);  \
        const bool upd = ((t) < len_n);                                           \
        _Pragma("unroll")                                                         \
        for (int i = 0; i < 4; ++i) {                                             \
            float v0 = tanh_scaled(aE0[i] + aO0[i]);                              \
            float v1 = tanh_scaled(aE1[i] + aO1[i]);                              \
            hreg[i]     = upd ? v0 : hreg[i];                                     \
            hreg[4 + i] = upd ? v1 : hreg[4 + i];                                 \
        }                                                                         \
        uint4 pk;                                                                 \
        pk.x = pk_u32(__builtin_amdgcn_cvt_pkrtz(hreg[0], hreg[1]));              \
        pk.y = pk_u32(__builtin_amdgcn_cvt_pkrtz(hreg[2], hreg[3]));              \
        pk.z = pk_u32(__builtin_amdgcn_cvt_pkrtz(hreg[4], hreg[5]));              \
        pk.w = pk_u32(__builtin_amdgcn_cvt_pkrtz(hreg[6], hreg[7]));              \
        exB[BW][w][lane] = pk;                                                    \
        xeC = xeN; idN = idN2;                                                    \
        __syncthreads();                                                          \
    }

    int t = 0;
    for (; t + 2 <= Lmax; t += 2) {
        RNN_STEP(0, 1, t);
        RNN_STEP(1, 0, t + 1);
    }
    if (t < Lmax) {
        RNN_STEP(0, 1, t);
    }
    #undef RNN_STEP

    // ---- publish final fp32 h: lane (q,n) of wave w holds features 32w+8q+0..7
    {
        float4 f0, f1;
        f0.x = hreg[0]; f0.y = hreg[1]; f0.z = hreg[2]; f0.w = hreg[3];
        f1.x = hreg[4]; f1.y = hreg[5]; f1.z = hreg[6]; f1.w = hreg[7];
        *(float4*)&sHf[n * HFSTR + 32 * w + 8 * q]     = f0;
        *(float4*)&sHf[n * HFSTR + 32 * w + 8 * q + 4] = f1;
    }
    __syncthreads();

    // ---- epilogue: logits = relu(h) @ W_out^T + b_out, then log_softmax
    for (int it = tid; it < ROWS * On; it += NTHR) {
        int r = it / On, c = it % On;
        float acc = b_out[c];
        for (int k = 0; k < Hn; ++k) {
            float hv = sHf[r * HFSTR + k];
            hv = hv > 0.0f ? hv : 0.0f;
            acc = fmaf(hv, W_out[c * Hn + k], acc);
        }
        sLogit[r][c] = acc;
    }
    __syncthreads();

    if (tid < ROWS) {
        float m = -INFINITY;
        #pragma unroll
        for (int c = 0; c < On; ++c) m = fmaxf(m, sLogit[tid][c]);
        float s = 0.0f;
        #pragma unroll
        for (int c = 0; c < On; ++c) s += __expf(sLogit[tid][c] - m);
        sMLS[tid] = m + __logf(s);
    }
    __syncthreads();

    for (int it = tid; it < ROWS * On; it += NTHR) {
        int r = it / On, c = it % On;
        out[(row0 + r) * On + c] = sLogit[r][c] - sMLS[r];
    }
}

extern "C" void kernel_launch(void* const* d_in, const int* in_sizes, int n_in,
                              void* d_out, int out_size, void* d_ws, size_t ws_size,
                              hipStream_t stream) {
    const int*   x     = (const int*)d_in[0];
    const int*   xlen  = (const int*)d_in[1];
    const float* emb   = (const float*)d_in[2];
    const float* W_ih  = (const float*)d_in[3];
    const float* W_hh  = (const float*)d_in[4];
    const float* b_ih  = (const float*)d_in[5];
    const float* b_hh  = (const float*)d_in[6];
    const float* W_out = (const float*)d_in[7];
    const float* b_out = (const float*)d_in[8];
    float*       out   = (float*)d_out;

    rnn_mfma_kernel<<<NBLK, NTHR, 0, stream>>>(x, xlen, emb, W_ih, W_hh,
                                               b_ih, b_hh, W_out, b_out, out);
}

// Round 2
// 231.467 us; speedup vs baseline: 1.2457x; 1.2457x over previous
//
#include <hip/hip_runtime.h>
#include <math.h>

#define Bn 4096
#define Tn 512
#define Vn 57
#define En 20
#define Hn 128
#define On 18
#define ROWS 16          // batch rows per block (= MFMA N)
#define NTHR 512         // 8 waves = 2/SIMD: co-resident wave hides per-step latency
#define NBLK (Bn / ROWS) // 256 blocks -> 1 per CU (LDS pad keeps it that way)
#define KC 5             // A K-chunks: 4x32 (W_hh) + 1x32 (W_ih 20 + bias 1 + 11 zero)
#define ESTR 40          // embT row stride (halfs)
#define XSTR 513         // staged x row stride (ints): bank=(r+t)%32, conflict-free
#define HFSTR 132        // final-h fp32 row stride
#define ASCALE 2.8853900817779268f   // 2*log2(e): folds tanh's 2x and log2e mul into A

typedef _Float16 half8  __attribute__((ext_vector_type(8)));
typedef __fp16   fp16x2 __attribute__((ext_vector_type(2)));   // cvt_pkrtz native type
typedef float    floatx4 __attribute__((ext_vector_type(4)));

// acc is pre-scaled by 2*log2e: tanh(x) = 1 - 2/(1+2^(2x*log2e))
__device__ __forceinline__ float tanh_scaled(float z) {
    float e = __builtin_amdgcn_exp2f(z);          // v_exp_f32
    float r = __builtin_amdgcn_rcpf(e + 1.0f);    // v_rcp_f32
    return fmaf(-2.0f, r, 1.0f);
}

__device__ __forceinline__ unsigned pk_u32(fp16x2 v) {
    union { fp16x2 h; unsigned u; } c; c.h = v; return c.u;
}

// (512, 2): 8 waves = 2/EU -> VGPR cap 256; demand ~80 -> no spill, full hiding.
__launch_bounds__(NTHR, 2)
__global__ void rnn_mfma_kernel(const int* __restrict__ x,
                                const int* __restrict__ xlen,
                                const float* __restrict__ emb,
                                const float* __restrict__ W_ih,
                                const float* __restrict__ W_hh,
                                const float* __restrict__ b_ih,
                                const float* __restrict__ b_hh,
                                const float* __restrict__ W_out,
                                const float* __restrict__ b_out,
                                float* __restrict__ out)
{
    // Exchange buffers: h-fragment kc for lane l at exB[buf][kc][l] (uint4=half8,
    // k = 32kc+8q+j, batch n; l = 16q+n). Reads: b128 stride-16B, conflict-free.
    // Writes: each wave contributes one uint2 half-slot (its 16 features land
    // in-place thanks to the A-row permutation). Double-buffered: 1 barrier/step.
    __shared__ __align__(16) uint4    exB[2][4][64];
    __shared__ __align__(16) _Float16 sEmb[Vn * ESTR];  // cols 0..19 emb, 20 = 1.0, rest 0
    __shared__ __align__(16) float    sHf[ROWS * HFSTR];
    __shared__ int   sX[ROWS * XSTR];
    __shared__ float sLogit[ROWS][On];
    __shared__ float sMLS[ROWS];
    __shared__ float sPad[6800];   // 27.2KB pad: total ~82.4KB -> exactly 1 block/CU

    const int tid  = threadIdx.x;
    const int blk  = blockIdx.x;
    const int row0 = blk * ROWS;

    // volatile touch keeps sPad (and the 1-block/CU LDS footprint) alive
    ((volatile float*)sPad)[tid % 6800] = 0.0f;

    const int w    = tid >> 6;       // wave 0..7 -> owns 16 h features (see map below)
    const int lane = tid & 63;
    const int n    = lane & 15;      // batch row (B/C col) AND A fragment row m
    const int q    = lane >> 4;      // quad
    const int kcW  = w >> 1;         // which 32-k fragment this wave's output feeds
    const int bsel = w & 1;          // which uint2 half of the 16B slot

    // ---- A operand (static, 20 VGPRs): PERMUTED row map so C output of wave w,
    // lane (q,n), reg i == h feature F = 32*kcW + 8q + 4*bsel + i. The packed
    // tanh output (uint2) is then EXACTLY the right 8B of B-fragment kcW --
    // no cross-lane shuffle, one ds_write_b64 per lane per step.
    //   A row m = lane&15 loads weight row F(m) = 32*kcW + 8*(m>>2) + 4*bsel + (m&3).
    // K order: k<128 W_hh col k; 128..147 W_ih; 148 fused bias (constant-1 xe col).
    // Pre-scaled by 2*log2e (tanh input fusion).
    half8 Ah[KC];
    const int f = 32 * kcW + 8 * (n >> 2) + 4 * bsel + (n & 3);
    #pragma unroll
    for (int kc = 0; kc < 4; ++kc) {
        const float* p = &W_hh[f * Hn + kc * 32 + q * 8];
        #pragma unroll
        for (int i = 0; i < 8; ++i)
            Ah[kc][i] = (_Float16)(p[i] * ASCALE);
    }
    #pragma unroll
    for (int i = 0; i < 8; ++i) {
        int e = q * 8 + i;
        float v = 0.0f;
        if (e < En)       v = W_ih[f * En + e];
        else if (e == 20) v = b_ih[f] + b_hh[f];
        Ah[4][i] = (_Float16)(v * ASCALE);
    }

    // ---- build embT (fp16) with constant-1 bias column
    for (int idx = tid; idx < Vn * 32; idx += NTHR) {
        int c = idx >> 5, j = idx & 31;
        float v = (j < En) ? emb[c * En + j] : (j == 20 ? 1.0f : 0.0f);
        sEmb[c * ESTR + j] = (_Float16)v;
    }
    // ---- stage vocab ids (int4-vectorized; 512 % 4 == 0 -> no row crossing)
    for (int idx = tid * 4; idx < ROWS * Tn; idx += NTHR * 4) {
        int4 v = *(const int4*)&x[row0 * Tn + idx];
        int r = idx >> 9, t = idx & 511;
        sX[r * XSTR + t]     = v.x;
        sX[r * XSTR + t + 1] = v.y;
        sX[r * XSTR + t + 2] = v.z;
        sX[r * XSTR + t + 3] = v.w;
    }
    // ---- zero both exchange buffers (h0 = 0)
    for (int idx = tid; idx < 2 * 4 * 64; idx += NTHR)
        ((uint4*)exB)[idx] = make_uint4(0u, 0u, 0u, 0u);
    __syncthreads();

    const int Lmax  = xlen[row0];    // sorted descending -> block trip count
    const int len_n = xlen[row0 + n];

    // ---- xe pipeline: lane (q,n) needs xe cols 8q..8q+7 of token x[n][t].
    // The xe MFMA partial for step t+1 is pre-accumulated BEFORE the barrier of
    // step t (xe is known ahead), shortening the post-barrier dependent chain.
    int     idN;
    floatx4 P = {0.f, 0.f, 0.f, 0.f};   // A4 . xe(t) partial for the upcoming step
    {
        int id0 = sX[n * XSTR];
        half8 xe0 = *(const half8*)&sEmb[id0 * ESTR + 8 * q];
        P = __builtin_amdgcn_mfma_f32_16x16x32_f16(Ah[4], xe0, P, 0, 0, 0);
        idN = sX[n * XSTR + (Lmax > 1 ? 1 : 0)];
    }

    float hreg[4] = {0.f, 0.f, 0.f, 0.f};

    const int wOffH = 32 * kcW + 8 * q + 4 * bsel;   // this lane's feature base

    // one step: read 4 h-frags, 4 MFMA on top of pre-computed xe partial
    // (aE depth 3 incl. P, aO depth 2), tanh+freeze+pack, one uint2 publish,
    // prefetch xe(t+1) partial, ONE barrier. Buffers compile-time (unroll by 2).
    #define RNN_STEP(BR, BW, t)                                                   \
    {                                                                             \
        half8 bf0 = *(const half8*)&exB[BR][0][lane];                             \
        half8 bf1 = *(const half8*)&exB[BR][1][lane];                             \
        half8 bf2 = *(const half8*)&exB[BR][2][lane];                             \
        half8 bf3 = *(const half8*)&exB[BR][3][lane];                             \
        floatx4 aE = P;                                                           \
        floatx4 aO = {0.f, 0.f, 0.f, 0.f};                                        \
        aE = __builtin_amdgcn_mfma_f32_16x16x32_f16(Ah[0], bf0, aE, 0, 0, 0);     \
        aO = __builtin_amdgcn_mfma_f32_16x16x32_f16(Ah[1], bf1, aO, 0, 0, 0);     \
        aE = __builtin_amdgcn_mfma_f32_16x16x32_f16(Ah[2], bf2, aE, 0, 0, 0);     \
        aO = __builtin_amdgcn_mfma_f32_16x16x32_f16(Ah[3], bf3, aO, 0, 0, 0);     \
        const bool upd = ((t) < len_n);                                           \
        _Pragma("unroll")                                                         \
        for (int i = 0; i < 4; ++i) {                                             \
            float v = tanh_scaled(aE[i] + aO[i]);                                 \
            hreg[i] = upd ? v : hreg[i];                                          \
        }                                                                         \
        uint2 pk;                                                                 \
        pk.x = pk_u32(__builtin_amdgcn_cvt_pkrtz(hreg[0], hreg[1]));              \
        pk.y = pk_u32(__builtin_amdgcn_cvt_pkrtz(hreg[2], hreg[3]));              \
        *(uint2*)((_Float16*)&exB[BW][kcW][0] + lane * 8 + 4 * bsel) = pk;        \
        half8 xeN = *(const half8*)&sEmb[idN * ESTR + 8 * q];                     \
        int tn = (t) + 2;                                                         \
        int idN2 = sX[n * XSTR + (tn < Lmax ? tn : Lmax - 1)];                    \
        floatx4 Pz = {0.f, 0.f, 0.f, 0.f};                                        \
        P = __builtin_amdgcn_mfma_f32_16x16x32_f16(Ah[4], xeN, Pz, 0, 0, 0);      \
        idN = idN2;                                                               \
        __syncthreads();                                                          \
    }

    int t = 0;
    for (; t + 2 <= Lmax; t += 2) {
        RNN_STEP(0, 1, t);
        RNN_STEP(1, 0, t + 1);
    }
    if (t < Lmax) {
        RNN_STEP(0, 1, t);
    }
    #undef RNN_STEP

    // ---- publish final fp32 h: lane (q,n) of wave w holds features wOffH+0..3
    {
        float4 f0;
        f0.x = hreg[0]; f0.y = hreg[1]; f0.z = hreg[2]; f0.w = hreg[3];
        *(float4*)&sHf[n * HFSTR + wOffH] = f0;
    }
    __syncthreads();

    // ---- epilogue: logits = relu(h) @ W_out^T + b_out, then log_softmax
    for (int it = tid; it < ROWS * On; it += NTHR) {
        int r = it / On, c = it % On;
        float acc = b_out[c];
        for (int k = 0; k < Hn; ++k) {
            float hv = sHf[r * HFSTR + k];
            hv = hv > 0.0f ? hv : 0.0f;
            acc = fmaf(hv, W_out[c * Hn + k], acc);
        }
        sLogit[r][c] = acc;
    }
    __syncthreads();

    if (tid < ROWS) {
        float m = -INFINITY;
        #pragma unroll
        for (int c = 0; c < On; ++c) m = fmaxf(m, sLogit[tid][c]);
        float s = 0.0f;
        #pragma unroll
        for (int c = 0; c < On; ++c) s += __expf(sLogit[tid][c] - m);
        sMLS[tid] = m + __logf(s);
    }
    __syncthreads();

    for (int it = tid; it < ROWS * On; it += NTHR) {
        int r = it / On, c = it % On;
        out[(row0 + r) * On + c] = sLogit[r][c] - sMLS[r];
    }
}

extern "C" void kernel_launch(void* const* d_in, const int* in_sizes, int n_in,
                              void* d_out, int out_size, void* d_ws, size_t ws_size,
                              hipStream_t stream) {
    const int*   x     = (const int*)d_in[0];
    const int*   xlen  = (const int*)d_in[1];
    const float* emb   = (const float*)d_in[2];
    const float* W_ih  = (const float*)d_in[3];
    const float* W_hh  = (const float*)d_in[4];
    const float* b_ih  = (const float*)d_in[5];
    const float* b_hh  = (const float*)d_in[6];
    const float* W_out = (const float*)d_in[7];
    const float* b_out = (const float*)d_in[8];
    float*       out   = (float*)d_out;

    rnn_mfma_kernel<<<NBLK, NTHR, 0, stream>>>(x, xlen, emb, W_ih, W_hh,
                                               b_ih, b_hh, W_out, b_out, out);
}